// Round 7
// baseline (286.629 us; speedup 1.0000x reference)
//
#include <hip/hip_runtime.h>
#include <hip/hip_bf16.h>

#define B_ 8
#define T_ 1024
#define IN_DIM_ 16
#define D_ 256
#define H_ 8
#define L_ 4
#define DK_ 32
#define BT_ (B_*T_)
#define LDT 72   // padded LDS stride for GEMM A tiles (BK=64)

typedef __attribute__((ext_vector_type(8))) __bf16 bf16x8;
typedef __attribute__((ext_vector_type(8))) unsigned short u16x8;
typedef __attribute__((ext_vector_type(4))) unsigned short u16x4;
typedef __attribute__((ext_vector_type(4))) float f32x4;
typedef __attribute__((ext_vector_type(4))) unsigned int u32x4;

static __device__ __forceinline__ unsigned short f2bf(float f) {
  union { float f; unsigned int u; } c{f};
  unsigned int u = c.u;
  u += 0x7fff + ((u >> 16) & 1);
  return (unsigned short)(u >> 16);
}
static __device__ __forceinline__ bf16x8 as_bf(u16x8 v) {
  return __builtin_bit_cast(bf16x8, v);
}

// ---------------- weight prep: f32 [z][R][C] -> bf16 [z][C][R] ----------------
__global__ __launch_bounds__(256) void k_wprep(
    const float* __restrict__ in, unsigned short* __restrict__ out,
    int R, int C) {
  __shared__ float tile[64][65];
  const float* inz = in + (size_t)blockIdx.z * R * C;
  unsigned short* outz = out + (size_t)blockIdx.z * R * C;
  int r0 = blockIdx.y * 64, c0 = blockIdx.x * 64;
  int tid = threadIdx.x;
  int tr = tid >> 2, tc = (tid & 3) * 16;
  #pragma unroll
  for (int i = 0; i < 16; i += 4) {
    float4 v = *(const float4*)(inz + (r0 + tr) * C + c0 + tc + i);
    tile[tr][tc + i] = v.x; tile[tr][tc + i + 1] = v.y;
    tile[tr][tc + i + 2] = v.z; tile[tr][tc + i + 3] = v.w;
  }
  __syncthreads();
  #pragma unroll
  for (int i = 0; i < 16; ++i)
    outz[(c0 + tr) * R + r0 + tc + i] = f2bf(tile[tc + i][tr]);
}

// ---------------- input projection: h = x@Wp + bp + pos ----------------
__global__ __launch_bounds__(256) void k_proj(
    const float* __restrict__ x, const float* __restrict__ Wp,
    const float* __restrict__ bp, const float* __restrict__ pos,
    float* __restrict__ h, unsigned short* __restrict__ hbf) {
  int row = blockIdx.x;            // bt
  int c = threadIdx.x;             // 0..255
  int t = row & (T_ - 1);
  float acc = bp[c] + pos[t * D_ + c];
  const float* xr = x + row * IN_DIM_;
  #pragma unroll
  for (int k = 0; k < IN_DIM_; ++k) acc += xr[k] * Wp[k * D_ + c];
  h[row * D_ + c] = acc;
  hbf[row * D_ + c] = f2bf(acc);
}

// ---------------- QKV GEMM: A staged in LDS, B direct from L2 ----------------
// q written PRE-SCALED by 1/sqrt(dk)*log2(e) -> attn does exp2(s) directly.
// q,k [b][h][t][dk]; v tiled-transposed [b][h][t/32][dk][32]
__global__ __launch_bounds__(256) void k_gemm_qkv(
    const unsigned short* __restrict__ A,    // BT x 256 bf16
    const unsigned short* __restrict__ Bt,   // 768 x 256 bf16 (W^T)
    const float* __restrict__ bias,          // 768
    unsigned short* __restrict__ qb, unsigned short* __restrict__ kb,
    unsigned short* __restrict__ vt) {
  __shared__ unsigned short As[64 * LDT];
  int row0 = blockIdx.x * 64;
  int col0 = blockIdx.y * 64;
  int tid = threadIdx.x;
  int lane = tid & 63, w = tid >> 6;
  int g = lane >> 4, li = lane & 15;
  int wr = (w >> 1) * 32, wc = (w & 1) * 32;
  f32x4 acc[2][2] = {};
  for (int k0 = 0; k0 < 256; k0 += 64) {
    __syncthreads();
    int r = tid >> 2, kk = (tid & 3) * 16;
    *(u16x8*)(As + r * LDT + kk)     = *(const u16x8*)(A + (row0 + r) * 256 + k0 + kk);
    *(u16x8*)(As + r * LDT + kk + 8) = *(const u16x8*)(A + (row0 + r) * 256 + k0 + kk + 8);
    __syncthreads();
    #pragma unroll
    for (int ks = 0; ks < 2; ++ks) {
      bf16x8 af[2], bfr[2];
      #pragma unroll
      for (int m = 0; m < 2; ++m)
        af[m] = as_bf(*(const u16x8*)(As + (wr + m * 16 + li) * LDT + ks * 32 + g * 8));
      #pragma unroll
      for (int n = 0; n < 2; ++n)
        bfr[n] = as_bf(*(const u16x8*)(
            Bt + (col0 + wc + n * 16 + li) * 256 + k0 + ks * 32 + g * 8));
      #pragma unroll
      for (int m = 0; m < 2; ++m)
        #pragma unroll
        for (int n = 0; n < 2; ++n)
          acc[m][n] = __builtin_amdgcn_mfma_f32_16x16x32_bf16(af[m], bfr[n], acc[m][n], 0, 0, 0);
    }
  }
  const float QSC = 0.25505654f;  // (1/sqrt(32)) * log2(e)
  #pragma unroll
  for (int m = 0; m < 2; ++m)
    #pragma unroll
    for (int n = 0; n < 2; ++n) {
      int c = col0 + wc + n * 16 + li;
      int rbase = row0 + wr + m * 16 + g * 4;
      int b = rbase >> 10, t = rbase & (T_ - 1);
      int s = c >> 8, rem = c & 255, hh = rem >> 5, dk = rem & 31;
      if (s == 0) {
        #pragma unroll
        for (int j = 0; j < 4; ++j) {
          float v = (acc[m][n][j] + bias[c]) * QSC;
          qb[(((b * H_ + hh) * T_) + t + j) * DK_ + dk] = f2bf(v);
        }
      } else if (s == 1) {
        #pragma unroll
        for (int j = 0; j < 4; ++j) {
          float v = acc[m][n][j] + bias[c];
          kb[(((b * H_ + hh) * T_) + t + j) * DK_ + dk] = f2bf(v);
        }
      } else {
        u16x4 pk;
        #pragma unroll
        for (int j = 0; j < 4; ++j) pk[j] = f2bf(acc[m][n][j] + bias[c]);
        // tiled V^T: [bh][t>>5][dk][t&31]
        *(u16x4*)(vt + (b * H_ + hh) * (DK_ * T_) +
                  ((t >> 5) * DK_ + dk) * 32 + (t & 31)) = pk;
      }
    }
}

// ---------------- attention: split-K flash, zero-LDS inner loop (R5 config) ----
__global__ __launch_bounds__(128) void k_attn(
    const unsigned short* __restrict__ qb, const unsigned short* __restrict__ kb,
    const unsigned short* __restrict__ vt, unsigned short* __restrict__ ob) {
  __shared__ float Osh[2][16][34];
  __shared__ float Lsh[2][16];
  int bh = blockIdx.y;
  int tid = threadIdx.x, lane = tid & 63, w = tid >> 6;  // w = k-half
  int g = lane >> 4, li = lane & 15;
  int q0 = blockIdx.x * 16;
  const unsigned short* Qp = qb + (bh * T_ + q0) * DK_;
  const unsigned short* Kp = kb + bh * T_ * DK_;
  const unsigned short* Vt = vt + bh * DK_ * T_;
  bf16x8 aq = as_bf(*(const u16x8*)(Qp + li * DK_ + g * 8));
  float l_run = 0.f;                         // lane-local partial denom (q = li)
  f32x4 oacc[2] = {};                        // O[q=g*4+j][dk=dh*16+li]
  for (int kt = w * 512; kt < (w + 1) * 512; kt += 32) {
    bf16x8 bk0 = as_bf(*(const u16x8*)(Kp + (kt + li) * DK_ + g * 8));
    bf16x8 bk1 = as_bf(*(const u16x8*)(Kp + (kt + 16 + li) * DK_ + g * 8));
    const unsigned short* vtile = Vt + (kt >> 5) * (DK_ * 32);
    bf16x8 bv0 = as_bf(*(const u16x8*)(vtile + li * 32 + g * 8));
    bf16x8 bv1 = as_bf(*(const u16x8*)(vtile + (16 + li) * 32 + g * 8));
    f32x4 s0 = {}, s1 = {};
    __builtin_amdgcn_s_setprio(1);
    s0 = __builtin_amdgcn_mfma_f32_16x16x32_bf16(bk0, aq, s0, 0, 0, 0);
    s1 = __builtin_amdgcn_mfma_f32_16x16x32_bf16(bk1, aq, s1, 0, 0, 0);
    __builtin_amdgcn_s_setprio(0);
    float p0[4], p1[4];
    #pragma unroll
    for (int j = 0; j < 4; ++j) {
      p0[j] = __builtin_amdgcn_exp2f(s0[j]);
      p1[j] = __builtin_amdgcn_exp2f(s1[j]);
    }
    l_run += ((p0[0] + p0[1]) + (p0[2] + p0[3])) +
             ((p1[0] + p1[1]) + (p1[2] + p1[3]));
    unsigned int c0, c1, c2, c3;
    asm("v_cvt_pk_bf16_f32 %0, %1, %2" : "=v"(c0) : "v"(p0[0]), "v"(p0[1]));
    asm("v_cvt_pk_bf16_f32 %0, %1, %2" : "=v"(c1) : "v"(p0[2]), "v"(p0[3]));
    asm("v_cvt_pk_bf16_f32 %0, %1, %2" : "=v"(c2) : "v"(p1[0]), "v"(p1[1]));
    asm("v_cvt_pk_bf16_f32 %0, %1, %2" : "=v"(c3) : "v"(p1[2]), "v"(p1[3]));
    asm("v_permlane32_swap_b32 %0, %1" : "+v"(c0), "+v"(c2));
    asm("v_permlane32_swap_b32 %0, %1" : "+v"(c1), "+v"(c3));
    asm("v_permlane16_swap_b32 %0, %1" : "+v"(c0), "+v"(c2));
    asm("v_permlane16_swap_b32 %0, %1" : "+v"(c1), "+v"(c3));
    u32x4 paw; paw[0] = c0; paw[1] = c1; paw[2] = c2; paw[3] = c3;
    bf16x8 pa = __builtin_bit_cast(bf16x8, paw);
    __builtin_amdgcn_s_setprio(1);
    oacc[0] = __builtin_amdgcn_mfma_f32_16x16x32_bf16(pa, bv0, oacc[0], 0, 0, 0);
    oacc[1] = __builtin_amdgcn_mfma_f32_16x16x32_bf16(pa, bv1, oacc[1], 0, 0, 0);
    __builtin_amdgcn_s_setprio(0);
  }
  l_run += __shfl_xor(l_run, 16);
  l_run += __shfl_xor(l_run, 32);
  #pragma unroll
  for (int dh = 0; dh < 2; ++dh)
    #pragma unroll
    for (int j = 0; j < 4; ++j)
      Osh[w][g * 4 + j][dh * 16 + li] = oacc[dh][j];
  if (g == 0) Lsh[w][li] = l_run;
  __syncthreads();
  int b = bh >> 3, hh = bh & 7;
  #pragma unroll
  for (int j = 0; j < 4; ++j) {
    int q = g * 4 + j;
    int dk = w * 16 + li;
    float o = Osh[0][q][dk] + Osh[1][q][dk];
    float l = Lsh[0][q] + Lsh[1][q];
    ob[((b * T_ + q0 + q) * H_ + hh) * DK_ + dk] = f2bf(o / l);
  }
}

// ------- fused out-proj + residual + LayerNorm: h = LN(ob@Wout+bout+h) -------
// Block = 16 rows, 2 waves; wave w computes 16 rows x cols [w*128, w*128+128).
// A fragments + B fragments loaded directly from global (L2-resident weight).
// Row stats: in-lane over 8 fragments + shfl_xor(1,2,4,8) + tiny LDS combine.
__global__ __launch_bounds__(128) void k_outln(
    const unsigned short* __restrict__ A,    // BT x 256 bf16 (attn out)
    const unsigned short* __restrict__ Bt,   // 256 x 256 bf16 (W^T)
    const float* __restrict__ bias,          // 256
    const float* __restrict__ gg, const float* __restrict__ bb,
    float* __restrict__ h,                   // in: residual, out: LN result
    unsigned short* __restrict__ hbf) {
  __shared__ float Ssh[2][16], Qsh[2][16];
  int tid = threadIdx.x, lane = tid & 63, w = tid >> 6;
  int g = lane >> 4, li = lane & 15;
  int row0 = blockIdx.x * 16;
  int c0 = w * 128;
  f32x4 acc[8] = {};
  for (int k0 = 0; k0 < 256; k0 += 32) {
    bf16x8 af = as_bf(*(const u16x8*)(A + (row0 + li) * 256 + k0 + g * 8));
    #pragma unroll
    for (int n = 0; n < 8; ++n) {
      bf16x8 bf = as_bf(*(const u16x8*)(Bt + (c0 + n * 16 + li) * 256 + k0 + g * 8));
      acc[n] = __builtin_amdgcn_mfma_f32_16x16x32_bf16(af, bf, acc[n], 0, 0, 0);
    }
  }
  // u = acc + bias + residual; per-row partial stats
  float uv[8][4];
  float s[4] = {0.f, 0.f, 0.f, 0.f}, q[4] = {0.f, 0.f, 0.f, 0.f};
  #pragma unroll
  for (int n = 0; n < 8; ++n) {
    int c = c0 + n * 16 + li;
    float bs = bias[c];
    #pragma unroll
    for (int j = 0; j < 4; ++j) {
      int r = row0 + g * 4 + j;
      float v = acc[n][j] + bs + h[r * 256 + c];
      uv[n][j] = v;
      s[j] += v; q[j] += v * v;
    }
  }
  #pragma unroll
  for (int j = 0; j < 4; ++j) {
    #pragma unroll
    for (int o = 1; o < 16; o <<= 1) {
      s[j] += __shfl_xor(s[j], o);
      q[j] += __shfl_xor(q[j], o);
    }
  }
  if (li == 0) {
    #pragma unroll
    for (int j = 0; j < 4; ++j) { Ssh[w][g * 4 + j] = s[j]; Qsh[w][g * 4 + j] = q[j]; }
  }
  __syncthreads();
  #pragma unroll
  for (int j = 0; j < 4; ++j) {
    int r = g * 4 + j;
    float st = Ssh[0][r] + Ssh[1][r];
    float qt = Qsh[0][r] + Qsh[1][r];
    float mean = st * (1.0f / D_);
    float var = qt * (1.0f / D_) - mean * mean;
    float rstd = rsqrtf(var + 1e-5f);
    s[j] = mean; q[j] = rstd;
  }
  #pragma unroll
  for (int n = 0; n < 8; ++n) {
    int c = c0 + n * 16 + li;
    float gv = gg[c], bv = bb[c];
    #pragma unroll
    for (int j = 0; j < 4; ++j) {
      int r = row0 + g * 4 + j;
      float y = (uv[n][j] - s[j]) * q[j] * gv + bv;
      h[r * 256 + c] = y;
      hbf[r * 256 + c] = f2bf(y);
    }
  }
}

// ---------------- final: out = h[:, -1, :] @ Wo + bo ----------------
__global__ void k_final(const float* __restrict__ h, const float* __restrict__ Wo,
                        const float* __restrict__ bo, float* __restrict__ out) {
  int tid = threadIdx.x;
  if (tid >= B_ * 3) return;
  int b = tid / 3, j = tid % 3;
  const float* hr = h + (b * T_ + (T_ - 1)) * D_;
  float acc = bo[j];
  for (int k = 0; k < D_; ++k) acc += hr[k] * Wo[k * 3 + j];
  out[tid] = acc;
}

extern "C" void kernel_launch(void* const* d_in, const int* in_sizes, int n_in,
                              void* d_out, int out_size, void* d_ws, size_t ws_size,
                              hipStream_t stream) {
  const float* x    = (const float*)d_in[0];
  const float* Wp   = (const float*)d_in[1];
  const float* bp   = (const float*)d_in[2];
  const float* pos  = (const float*)d_in[3];
  const float* Wqkv = (const float*)d_in[4];
  const float* bqkv = (const float*)d_in[5];
  const float* Wout = (const float*)d_in[6];
  const float* bout = (const float*)d_in[7];
  const float* ln_g = (const float*)d_in[8];
  const float* ln_b = (const float*)d_in[9];
  const float* Wo   = (const float*)d_in[10];
  const float* bo   = (const float*)d_in[11];

  char* ws = (char*)d_ws;
  float* h            = (float*)(ws);                        // 8 MB
  unsigned short* hbf = (unsigned short*)(ws + (16u << 20)); // 4 MB
  unsigned short* qb  = (unsigned short*)(ws + (20u << 20)); // 4 MB
  unsigned short* kb  = (unsigned short*)(ws + (24u << 20)); // 4 MB
  unsigned short* vt  = (unsigned short*)(ws + (28u << 20)); // 4 MB (tiled V^T)
  unsigned short* ob  = (unsigned short*)(ws + (32u << 20)); // 4 MB
  unsigned short* WqkvT = (unsigned short*)(ws + (36u << 20)); // 1.5 MB
  unsigned short* WoutT = (unsigned short*)(ws + (38u << 20)); // 0.5 MB

  k_wprep<<<dim3(12, 4, 4), 256, 0, stream>>>(Wqkv, WqkvT, 256, 768);
  k_wprep<<<dim3(4, 4, 4), 256, 0, stream>>>(Wout, WoutT, 256, 256);
  k_proj<<<BT_, 256, 0, stream>>>(x, Wp, bp, pos, h, hbf);
  for (int l = 0; l < L_; ++l) {
    k_gemm_qkv<<<dim3(BT_ / 64, 12), 256, 0, stream>>>(
        hbf, WqkvT + l * 768 * 256, bqkv + l * 768, qb, kb, vt);
    k_attn<<<dim3(T_ / 16, B_ * H_), 128, 0, stream>>>(qb, kb, vt, ob);
    k_outln<<<BT_ / 16, 128, 0, stream>>>(
        ob, WoutT + l * 256 * 256, bout + l * 256,
        ln_g + l * 256, ln_b + l * 256, h, hbf);
  }
  k_final<<<1, 64, 0, stream>>>(h, Wo, bo, (float*)d_out);
}

// Round 8
// 232.187 us; speedup vs baseline: 1.2345x; 1.2345x over previous
//
#include <hip/hip_runtime.h>
#include <hip/hip_bf16.h>

#define B_ 8
#define T_ 1024
#define IN_DIM_ 16
#define D_ 256
#define H_ 8
#define L_ 4
#define DK_ 32
#define BT_ (B_*T_)
#define LDT 72   // padded LDS stride for GEMM tiles (BK=64)

typedef __attribute__((ext_vector_type(8))) __bf16 bf16x8;
typedef __attribute__((ext_vector_type(8))) unsigned short u16x8;
typedef __attribute__((ext_vector_type(4))) unsigned short u16x4;
typedef __attribute__((ext_vector_type(4))) float f32x4;
typedef __attribute__((ext_vector_type(4))) unsigned int u32x4;

static __device__ __forceinline__ unsigned short f2bf(float f) {
  union { float f; unsigned int u; } c{f};
  unsigned int u = c.u;
  u += 0x7fff + ((u >> 16) & 1);
  return (unsigned short)(u >> 16);
}
static __device__ __forceinline__ bf16x8 as_bf(u16x8 v) {
  return __builtin_bit_cast(bf16x8, v);
}

// ---------------- weight prep: f32 [z][R][C] -> bf16 [z][C][R] ----------------
__global__ __launch_bounds__(256) void k_wprep(
    const float* __restrict__ in, unsigned short* __restrict__ out,
    int R, int C) {
  __shared__ float tile[64][65];
  const float* inz = in + (size_t)blockIdx.z * R * C;
  unsigned short* outz = out + (size_t)blockIdx.z * R * C;
  int r0 = blockIdx.y * 64, c0 = blockIdx.x * 64;
  int tid = threadIdx.x;
  int tr = tid >> 2, tc = (tid & 3) * 16;
  #pragma unroll
  for (int i = 0; i < 16; i += 4) {
    float4 v = *(const float4*)(inz + (r0 + tr) * C + c0 + tc + i);
    tile[tr][tc + i] = v.x; tile[tr][tc + i + 1] = v.y;
    tile[tr][tc + i + 2] = v.z; tile[tr][tc + i + 3] = v.w;
  }
  __syncthreads();
  #pragma unroll
  for (int i = 0; i < 16; ++i)
    outz[(c0 + tr) * R + r0 + tc + i] = f2bf(tile[tc + i][tr]);
}

// ---------------- input projection: h = x@Wp + bp + pos ----------------
__global__ __launch_bounds__(256) void k_proj(
    const float* __restrict__ x, const float* __restrict__ Wp,
    const float* __restrict__ bp, const float* __restrict__ pos,
    float* __restrict__ h, unsigned short* __restrict__ hbf) {
  int row = blockIdx.x;            // bt
  int c = threadIdx.x;             // 0..255
  int t = row & (T_ - 1);
  float acc = bp[c] + pos[t * D_ + c];
  const float* xr = x + row * IN_DIM_;
  #pragma unroll
  for (int k = 0; k < IN_DIM_; ++k) acc += xr[k] * Wp[k * D_ + c];
  h[row * D_ + c] = acc;
  hbf[row * D_ + c] = f2bf(acc);
}

// ---------------- QKV GEMM: (BTx256 bf16) x (768x256 bf16 W^T) ----------------
// q written PRE-SCALED by 1/sqrt(dk)*log2(e) -> attn does exp2(s) directly.
// q,k [b][h][t][dk]; v tiled-transposed [b][h][t/32][dk][32]
__global__ __launch_bounds__(256) void k_gemm_qkv(
    const unsigned short* __restrict__ A,    // BT x 256 bf16
    const unsigned short* __restrict__ Bt,   // 768 x 256 bf16 (W^T)
    const float* __restrict__ bias,          // 768
    unsigned short* __restrict__ qb, unsigned short* __restrict__ kb,
    unsigned short* __restrict__ vt) {
  __shared__ unsigned short As[64 * LDT];
  __shared__ unsigned short Bs[64 * LDT];
  int row0 = blockIdx.x * 64;
  int col0 = blockIdx.y * 64;
  int tid = threadIdx.x;
  int lane = tid & 63, w = tid >> 6;
  int g = lane >> 4, li = lane & 15;
  int wr = (w >> 1) * 32, wc = (w & 1) * 32;
  f32x4 acc[2][2] = {};
  for (int k0 = 0; k0 < 256; k0 += 64) {
    __syncthreads();
    int r = tid >> 2, kk = (tid & 3) * 16;
    *(u16x8*)(As + r * LDT + kk)     = *(const u16x8*)(A + (row0 + r) * 256 + k0 + kk);
    *(u16x8*)(As + r * LDT + kk + 8) = *(const u16x8*)(A + (row0 + r) * 256 + k0 + kk + 8);
    *(u16x8*)(Bs + r * LDT + kk)     = *(const u16x8*)(Bt + (col0 + r) * 256 + k0 + kk);
    *(u16x8*)(Bs + r * LDT + kk + 8) = *(const u16x8*)(Bt + (col0 + r) * 256 + k0 + kk + 8);
    __syncthreads();
    #pragma unroll
    for (int ks = 0; ks < 2; ++ks) {
      bf16x8 af[2], bfr[2];
      #pragma unroll
      for (int m = 0; m < 2; ++m)
        af[m] = as_bf(*(const u16x8*)(As + (wr + m * 16 + li) * LDT + ks * 32 + g * 8));
      #pragma unroll
      for (int n = 0; n < 2; ++n)
        bfr[n] = as_bf(*(const u16x8*)(Bs + (wc + n * 16 + li) * LDT + ks * 32 + g * 8));
      #pragma unroll
      for (int m = 0; m < 2; ++m)
        #pragma unroll
        for (int n = 0; n < 2; ++n)
          acc[m][n] = __builtin_amdgcn_mfma_f32_16x16x32_bf16(af[m], bfr[n], acc[m][n], 0, 0, 0);
    }
  }
  const float QSC = 0.25505654f;  // (1/sqrt(32)) * log2(e)
  #pragma unroll
  for (int m = 0; m < 2; ++m)
    #pragma unroll
    for (int n = 0; n < 2; ++n) {
      int c = col0 + wc + n * 16 + li;
      int rbase = row0 + wr + m * 16 + g * 4;
      int b = rbase >> 10, t = rbase & (T_ - 1);
      int s = c >> 8, rem = c & 255, hh = rem >> 5, dk = rem & 31;
      if (s == 0) {
        #pragma unroll
        for (int j = 0; j < 4; ++j) {
          float v = (acc[m][n][j] + bias[c]) * QSC;
          qb[(((b * H_ + hh) * T_) + t + j) * DK_ + dk] = f2bf(v);
        }
      } else if (s == 1) {
        #pragma unroll
        for (int j = 0; j < 4; ++j) {
          float v = acc[m][n][j] + bias[c];
          kb[(((b * H_ + hh) * T_) + t + j) * DK_ + dk] = f2bf(v);
        }
      } else {
        u16x4 pk;
        #pragma unroll
        for (int j = 0; j < 4; ++j) pk[j] = f2bf(acc[m][n][j] + bias[c]);
        // tiled V^T: [bh][t>>5][dk][t&31]
        *(u16x4*)(vt + (b * H_ + hh) * (DK_ * T_) +
                  ((t >> 5) * DK_ + dk) * 32 + (t & 31)) = pk;
      }
    }
}

// ---- attention: 32 q-rows/wave (2 Q frags), 4-wave 4-way split-K, zero-LDS loop
// Keeps R5's 8192-wave occupancy; halves K/V L2 traffic; 2 independent chains
// per iter. Partials (O,l) additive (no online max), combined via LDS.
__global__ __launch_bounds__(256) void k_attn(
    const unsigned short* __restrict__ qb, const unsigned short* __restrict__ kb,
    const unsigned short* __restrict__ vt, unsigned short* __restrict__ ob) {
  __shared__ float Osh[4][32][33];
  __shared__ float Lsh[4][32];
  int bh = blockIdx.y;
  int tid = threadIdx.x, lane = tid & 63, w = tid >> 6;  // w = k-quarter
  int g = lane >> 4, li = lane & 15;
  int q0 = blockIdx.x * 32;
  const unsigned short* Qp = qb + (bh * T_ + q0) * DK_;
  const unsigned short* Kp = kb + bh * T_ * DK_;
  const unsigned short* Vt = vt + bh * DK_ * T_;
  bf16x8 aq0 = as_bf(*(const u16x8*)(Qp + li * DK_ + g * 8));
  bf16x8 aq1 = as_bf(*(const u16x8*)(Qp + (16 + li) * DK_ + g * 8));
  float l_run0 = 0.f, l_run1 = 0.f;          // lane-local partial denom (q = li)
  f32x4 oacc0[2] = {}, oacc1[2] = {};        // O[q=g*4+j][dk=dh*16+li]
  for (int kt = w * 256; kt < (w + 1) * 256; kt += 32) {
    bf16x8 bk0 = as_bf(*(const u16x8*)(Kp + (kt + li) * DK_ + g * 8));
    bf16x8 bk1 = as_bf(*(const u16x8*)(Kp + (kt + 16 + li) * DK_ + g * 8));
    const unsigned short* vtile = Vt + (kt >> 5) * (DK_ * 32);
    bf16x8 bv0 = as_bf(*(const u16x8*)(vtile + li * 32 + g * 8));
    bf16x8 bv1 = as_bf(*(const u16x8*)(vtile + (16 + li) * 32 + g * 8));
    f32x4 s0 = {}, s1 = {}, t0 = {}, t1 = {};
    __builtin_amdgcn_s_setprio(1);
    s0 = __builtin_amdgcn_mfma_f32_16x16x32_bf16(bk0, aq0, s0, 0, 0, 0);
    s1 = __builtin_amdgcn_mfma_f32_16x16x32_bf16(bk1, aq0, s1, 0, 0, 0);
    t0 = __builtin_amdgcn_mfma_f32_16x16x32_bf16(bk0, aq1, t0, 0, 0, 0);
    t1 = __builtin_amdgcn_mfma_f32_16x16x32_bf16(bk1, aq1, t1, 0, 0, 0);
    __builtin_amdgcn_s_setprio(0);
    // chain 0 (q rows 0..15)
    {
      float p0[4], p1[4];
      #pragma unroll
      for (int j = 0; j < 4; ++j) {
        p0[j] = __builtin_amdgcn_exp2f(s0[j]);
        p1[j] = __builtin_amdgcn_exp2f(s1[j]);
      }
      l_run0 += ((p0[0] + p0[1]) + (p0[2] + p0[3])) +
                ((p1[0] + p1[1]) + (p1[2] + p1[3]));
      unsigned int c0, c1, c2, c3;
      asm("v_cvt_pk_bf16_f32 %0, %1, %2" : "=v"(c0) : "v"(p0[0]), "v"(p0[1]));
      asm("v_cvt_pk_bf16_f32 %0, %1, %2" : "=v"(c1) : "v"(p0[2]), "v"(p0[3]));
      asm("v_cvt_pk_bf16_f32 %0, %1, %2" : "=v"(c2) : "v"(p1[0]), "v"(p1[1]));
      asm("v_cvt_pk_bf16_f32 %0, %1, %2" : "=v"(c3) : "v"(p1[2]), "v"(p1[3]));
      asm("v_permlane32_swap_b32 %0, %1" : "+v"(c0), "+v"(c2));
      asm("v_permlane32_swap_b32 %0, %1" : "+v"(c1), "+v"(c3));
      asm("v_permlane16_swap_b32 %0, %1" : "+v"(c0), "+v"(c2));
      asm("v_permlane16_swap_b32 %0, %1" : "+v"(c1), "+v"(c3));
      u32x4 paw; paw[0] = c0; paw[1] = c1; paw[2] = c2; paw[3] = c3;
      bf16x8 pa = __builtin_bit_cast(bf16x8, paw);
      __builtin_amdgcn_s_setprio(1);
      oacc0[0] = __builtin_amdgcn_mfma_f32_16x16x32_bf16(pa, bv0, oacc0[0], 0, 0, 0);
      oacc0[1] = __builtin_amdgcn_mfma_f32_16x16x32_bf16(pa, bv1, oacc0[1], 0, 0, 0);
      __builtin_amdgcn_s_setprio(0);
    }
    // chain 1 (q rows 16..31)
    {
      float p0[4], p1[4];
      #pragma unroll
      for (int j = 0; j < 4; ++j) {
        p0[j] = __builtin_amdgcn_exp2f(t0[j]);
        p1[j] = __builtin_amdgcn_exp2f(t1[j]);
      }
      l_run1 += ((p0[0] + p0[1]) + (p0[2] + p0[3])) +
                ((p1[0] + p1[1]) + (p1[2] + p1[3]));
      unsigned int c0, c1, c2, c3;
      asm("v_cvt_pk_bf16_f32 %0, %1, %2" : "=v"(c0) : "v"(p0[0]), "v"(p0[1]));
      asm("v_cvt_pk_bf16_f32 %0, %1, %2" : "=v"(c1) : "v"(p0[2]), "v"(p0[3]));
      asm("v_cvt_pk_bf16_f32 %0, %1, %2" : "=v"(c2) : "v"(p1[0]), "v"(p1[1]));
      asm("v_cvt_pk_bf16_f32 %0, %1, %2" : "=v"(c3) : "v"(p1[2]), "v"(p1[3]));
      asm("v_permlane32_swap_b32 %0, %1" : "+v"(c0), "+v"(c2));
      asm("v_permlane32_swap_b32 %0, %1" : "+v"(c1), "+v"(c3));
      asm("v_permlane16_swap_b32 %0, %1" : "+v"(c0), "+v"(c2));
      asm("v_permlane16_swap_b32 %0, %1" : "+v"(c1), "+v"(c3));
      u32x4 paw; paw[0] = c0; paw[1] = c1; paw[2] = c2; paw[3] = c3;
      bf16x8 pa = __builtin_bit_cast(bf16x8, paw);
      __builtin_amdgcn_s_setprio(1);
      oacc1[0] = __builtin_amdgcn_mfma_f32_16x16x32_bf16(pa, bv0, oacc1[0], 0, 0, 0);
      oacc1[1] = __builtin_amdgcn_mfma_f32_16x16x32_bf16(pa, bv1, oacc1[1], 0, 0, 0);
      __builtin_amdgcn_s_setprio(0);
    }
  }
  // reduce partial denominators across the 4 replicated groups; stash partials
  l_run0 += __shfl_xor(l_run0, 16);
  l_run0 += __shfl_xor(l_run0, 32);
  l_run1 += __shfl_xor(l_run1, 16);
  l_run1 += __shfl_xor(l_run1, 32);
  if (g == 0) { Lsh[w][li] = l_run0; Lsh[w][16 + li] = l_run1; }
  #pragma unroll
  for (int dh = 0; dh < 2; ++dh)
    #pragma unroll
    for (int j = 0; j < 4; ++j) {
      Osh[w][g * 4 + j][dh * 16 + li] = oacc0[dh][j];
      Osh[w][16 + g * 4 + j][dh * 16 + li] = oacc1[dh][j];
    }
  __syncthreads();
  // combine the 4 k-quarters; threads 0..127: one q-row, one dk-octet
  if (tid < 128) {
    int q = tid & 31, dk0 = (tid >> 5) * 8;
    float l = (Lsh[0][q] + Lsh[1][q]) + (Lsh[2][q] + Lsh[3][q]);
    float rl = 1.0f / l;
    int b = bh >> 3, hh = bh & 7;
    u16x8 outv;
    #pragma unroll
    for (int i = 0; i < 8; ++i) {
      float o = (Osh[0][q][dk0 + i] + Osh[1][q][dk0 + i]) +
                (Osh[2][q][dk0 + i] + Osh[3][q][dk0 + i]);
      outv[i] = f2bf(o * rl);
    }
    *(u16x8*)(ob + ((b * T_ + q0 + q) * H_ + hh) * DK_ + dk0) = outv;
  }
}

// ---------------- out-proj GEMM: o@Wout + bout + residual -> u (f32) ----------------
__global__ __launch_bounds__(256) void k_gemm_out(
    const unsigned short* __restrict__ A,    // BT x 256 bf16 (attn out)
    const unsigned short* __restrict__ Bt,   // 256 x 256 bf16 (W^T)
    const float* __restrict__ bias,          // 256
    const float* __restrict__ hres,          // BT x 256 f32 residual
    float* __restrict__ u) {
  __shared__ unsigned short As[64 * LDT];
  __shared__ unsigned short Bs[64 * LDT];
  int row0 = blockIdx.x * 64;
  int col0 = blockIdx.y * 64;
  int tid = threadIdx.x;
  int lane = tid & 63, w = tid >> 6;
  int g = lane >> 4, li = lane & 15;
  int wr = (w >> 1) * 32, wc = (w & 1) * 32;
  f32x4 acc[2][2] = {};
  for (int k0 = 0; k0 < 256; k0 += 64) {
    __syncthreads();
    int r = tid >> 2, kk = (tid & 3) * 16;
    *(u16x8*)(As + r * LDT + kk)     = *(const u16x8*)(A + (row0 + r) * 256 + k0 + kk);
    *(u16x8*)(As + r * LDT + kk + 8) = *(const u16x8*)(A + (row0 + r) * 256 + k0 + kk + 8);
    *(u16x8*)(Bs + r * LDT + kk)     = *(const u16x8*)(Bt + (col0 + r) * 256 + k0 + kk);
    *(u16x8*)(Bs + r * LDT + kk + 8) = *(const u16x8*)(Bt + (col0 + r) * 256 + k0 + kk + 8);
    __syncthreads();
    #pragma unroll
    for (int ks = 0; ks < 2; ++ks) {
      bf16x8 af[2], bfr[2];
      #pragma unroll
      for (int m = 0; m < 2; ++m)
        af[m] = as_bf(*(const u16x8*)(As + (wr + m * 16 + li) * LDT + ks * 32 + g * 8));
      #pragma unroll
      for (int n = 0; n < 2; ++n)
        bfr[n] = as_bf(*(const u16x8*)(Bs + (wc + n * 16 + li) * LDT + ks * 32 + g * 8));
      #pragma unroll
      for (int m = 0; m < 2; ++m)
        #pragma unroll
        for (int n = 0; n < 2; ++n)
          acc[m][n] = __builtin_amdgcn_mfma_f32_16x16x32_bf16(af[m], bfr[n], acc[m][n], 0, 0, 0);
    }
  }
  #pragma unroll
  for (int m = 0; m < 2; ++m)
    #pragma unroll
    for (int n = 0; n < 2; ++n)
      #pragma unroll
      for (int j = 0; j < 4; ++j) {
        int r = row0 + wr + m * 16 + g * 4 + j;
        int c = col0 + wc + n * 16 + li;
        u[r * 256 + c] = acc[m][n][j] + bias[c] + hres[r * 256 + c];
      }
}

// ---------------- layernorm: h = LN(u)*g + b; also bf16 mirror ----------------
__global__ __launch_bounds__(256) void k_ln(
    const float* __restrict__ u, const float* __restrict__ gg,
    const float* __restrict__ bb, float* __restrict__ h,
    unsigned short* __restrict__ hbf) {
  int row = blockIdx.x;
  int c = threadIdx.x;
  float v = u[row * D_ + c];
  float s = v, q = v * v;
  #pragma unroll
  for (int o = 1; o < 64; o <<= 1) { s += __shfl_xor(s, o); q += __shfl_xor(q, o); }
  __shared__ float ls[4], lq[4];
  int w = threadIdx.x >> 6;
  if ((threadIdx.x & 63) == 0) { ls[w] = s; lq[w] = q; }
  __syncthreads();
  s = ls[0] + ls[1] + ls[2] + ls[3];
  q = lq[0] + lq[1] + lq[2] + lq[3];
  float mean = s * (1.0f / D_);
  float var = q * (1.0f / D_) - mean * mean;
  float rstd = rsqrtf(var + 1e-5f);
  float y = (v - mean) * rstd * gg[c] + bb[c];
  h[row * D_ + c] = y;
  hbf[row * D_ + c] = f2bf(y);
}

// ---------------- final: out = h[:, -1, :] @ Wo + bo ----------------
__global__ void k_final(const float* __restrict__ h, const float* __restrict__ Wo,
                        const float* __restrict__ bo, float* __restrict__ out) {
  int tid = threadIdx.x;
  if (tid >= B_ * 3) return;
  int b = tid / 3, j = tid % 3;
  const float* hr = h + (b * T_ + (T_ - 1)) * D_;
  float acc = bo[j];
  for (int k = 0; k < D_; ++k) acc += hr[k] * Wo[k * 3 + j];
  out[tid] = acc;
}

extern "C" void kernel_launch(void* const* d_in, const int* in_sizes, int n_in,
                              void* d_out, int out_size, void* d_ws, size_t ws_size,
                              hipStream_t stream) {
  const float* x    = (const float*)d_in[0];
  const float* Wp   = (const float*)d_in[1];
  const float* bp   = (const float*)d_in[2];
  const float* pos  = (const float*)d_in[3];
  const float* Wqkv = (const float*)d_in[4];
  const float* bqkv = (const float*)d_in[5];
  const float* Wout = (const float*)d_in[6];
  const float* bout = (const float*)d_in[7];
  const float* ln_g = (const float*)d_in[8];
  const float* ln_b = (const float*)d_in[9];
  const float* Wo   = (const float*)d_in[10];
  const float* bo   = (const float*)d_in[11];

  char* ws = (char*)d_ws;
  float* h            = (float*)(ws);                        // 8 MB
  float* u            = (float*)(ws + (8u << 20));           // 8 MB
  unsigned short* hbf = (unsigned short*)(ws + (16u << 20)); // 4 MB
  unsigned short* qb  = (unsigned short*)(ws + (20u << 20)); // 4 MB
  unsigned short* kb  = (unsigned short*)(ws + (24u << 20)); // 4 MB
  unsigned short* vt  = (unsigned short*)(ws + (28u << 20)); // 4 MB (tiled V^T)
  unsigned short* ob  = (unsigned short*)(ws + (32u << 20)); // 4 MB
  unsigned short* WqkvT = (unsigned short*)(ws + (36u << 20)); // 1.5 MB
  unsigned short* WoutT = (unsigned short*)(ws + (38u << 20)); // 0.5 MB

  k_wprep<<<dim3(12, 4, 4), 256, 0, stream>>>(Wqkv, WqkvT, 256, 768);
  k_wprep<<<dim3(4, 4, 4), 256, 0, stream>>>(Wout, WoutT, 256, 256);
  k_proj<<<BT_, 256, 0, stream>>>(x, Wp, bp, pos, h, hbf);
  for (int l = 0; l < L_; ++l) {
    k_gemm_qkv<<<dim3(BT_ / 64, 12), 256, 0, stream>>>(
        hbf, WqkvT + l * 768 * 256, bqkv + l * 768, qb, kb, vt);
    k_attn<<<dim3(T_ / 32, B_ * H_), 256, 0, stream>>>(qb, kb, vt, ob);
    k_gemm_out<<<dim3(BT_ / 64, 4), 256, 0, stream>>>(
        ob, WoutT + l * 256 * 256, bout + l * 256, h, u);
    k_ln<<<BT_, 256, 0, stream>>>(u, ln_g + l * 256, ln_b + l * 256, h, hbf);
  }
  k_final<<<1, 64, 0, stream>>>(h, Wo, bo, (float*)d_out);
}

// Round 9
// 230.695 us; speedup vs baseline: 1.2425x; 1.0065x over previous
//
#include <hip/hip_runtime.h>
#include <hip/hip_bf16.h>

#define B_ 8
#define T_ 1024
#define IN_DIM_ 16
#define D_ 256
#define H_ 8
#define L_ 4
#define DK_ 32
#define BT_ (B_*T_)
#define LDT 72   // padded LDS stride for GEMM A tiles (BK=64)

typedef __attribute__((ext_vector_type(8))) __bf16 bf16x8;
typedef __attribute__((ext_vector_type(8))) unsigned short u16x8;
typedef __attribute__((ext_vector_type(4))) unsigned short u16x4;
typedef __attribute__((ext_vector_type(4))) float f32x4;
typedef __attribute__((ext_vector_type(4))) unsigned int u32x4;

static __device__ __forceinline__ unsigned short f2bf(float f) {
  union { float f; unsigned int u; } c{f};
  unsigned int u = c.u;
  u += 0x7fff + ((u >> 16) & 1);
  return (unsigned short)(u >> 16);
}
static __device__ __forceinline__ bf16x8 as_bf(u16x8 v) {
  return __builtin_bit_cast(bf16x8, v);
}

// ------- weight prep: f32 W[z][K][N] -> bf16 fragment-tiled [z][N/16][K/32][16][32]
// Fragment (nb,kb) holds B-operand rows n=nb*16+li, cols k=kb*32+g*8+j in exact
// MFMA lane order -> a wave's fragment load is one contiguous 1KB segment.
__global__ __launch_bounds__(64) void k_wprep_f(
    const float* __restrict__ in, unsigned short* __restrict__ out,
    int K, int N) {
  int nb = blockIdx.x, kb = blockIdx.y, z = blockIdx.z;
  const float* inz = in + (size_t)z * K * N;
  unsigned short* outz = out + (size_t)z * K * N;
  int lane = threadIdx.x;
  int li = lane & 15, g = lane >> 4;
  int n = nb * 16 + li;
  int k0 = kb * 32 + g * 8;
  u16x8 v;
  #pragma unroll
  for (int j = 0; j < 8; ++j) v[j] = f2bf(inz[(k0 + j) * N + n]);
  *(u16x8*)(outz + ((nb * (K >> 5) + kb) << 9) + li * 32 + g * 8) = v;
}

// ---------------- input projection: h = x@Wp + bp + pos ----------------
__global__ __launch_bounds__(256) void k_proj(
    const float* __restrict__ x, const float* __restrict__ Wp,
    const float* __restrict__ bp, const float* __restrict__ pos,
    float* __restrict__ h, unsigned short* __restrict__ hbf) {
  int row = blockIdx.x;            // bt
  int c = threadIdx.x;             // 0..255
  int t = row & (T_ - 1);
  float acc = bp[c] + pos[t * D_ + c];
  const float* xr = x + row * IN_DIM_;
  #pragma unroll
  for (int k = 0; k < IN_DIM_; ++k) acc += xr[k] * Wp[k * D_ + c];
  h[row * D_ + c] = acc;
  hbf[row * D_ + c] = f2bf(acc);
}

// ------------- QKV GEMM: A staged in LDS, B fragment-tiled from L2 -------------
// q written PRE-SCALED by 1/sqrt(dk)*log2(e) -> attn does exp2(s) directly.
// q,k [b][h][t][dk]; v tiled-transposed [b][h][t/32][dk][32]
__global__ __launch_bounds__(256) void k_gemm_qkv(
    const unsigned short* __restrict__ A,    // BT x 256 bf16
    const unsigned short* __restrict__ Btf,  // ftiled [48][8][16][32]
    const float* __restrict__ bias,          // 768
    unsigned short* __restrict__ qb, unsigned short* __restrict__ kb,
    unsigned short* __restrict__ vt) {
  __shared__ unsigned short As[64 * LDT];
  int row0 = blockIdx.x * 64;
  int col0 = blockIdx.y * 64;
  int tid = threadIdx.x;
  int lane = tid & 63, w = tid >> 6;
  int g = lane >> 4, li = lane & 15;
  int wr = (w >> 1) * 32, wc = (w & 1) * 32;
  f32x4 acc[2][2] = {};
  for (int k0 = 0; k0 < 256; k0 += 64) {
    __syncthreads();
    int r = tid >> 2, kk = (tid & 3) * 16;
    *(u16x8*)(As + r * LDT + kk)     = *(const u16x8*)(A + (row0 + r) * 256 + k0 + kk);
    *(u16x8*)(As + r * LDT + kk + 8) = *(const u16x8*)(A + (row0 + r) * 256 + k0 + kk + 8);
    __syncthreads();
    #pragma unroll
    for (int ks = 0; ks < 2; ++ks) {
      int kblk = (k0 >> 5) + ks;
      bf16x8 af[2], bfr[2];
      #pragma unroll
      for (int m = 0; m < 2; ++m)
        af[m] = as_bf(*(const u16x8*)(As + (wr + m * 16 + li) * LDT + ks * 32 + g * 8));
      #pragma unroll
      for (int n = 0; n < 2; ++n) {
        int nblk = (blockIdx.y << 2) + ((w & 1) << 1) + n;
        bfr[n] = as_bf(*(const u16x8*)(Btf + ((nblk * 8 + kblk) << 9) + li * 32 + g * 8));
      }
      #pragma unroll
      for (int m = 0; m < 2; ++m)
        #pragma unroll
        for (int n = 0; n < 2; ++n)
          acc[m][n] = __builtin_amdgcn_mfma_f32_16x16x32_bf16(af[m], bfr[n], acc[m][n], 0, 0, 0);
    }
  }
  const float QSC = 0.25505654f;  // (1/sqrt(32)) * log2(e)
  #pragma unroll
  for (int m = 0; m < 2; ++m)
    #pragma unroll
    for (int n = 0; n < 2; ++n) {
      int c = col0 + wc + n * 16 + li;
      int rbase = row0 + wr + m * 16 + g * 4;
      int b = rbase >> 10, t = rbase & (T_ - 1);
      int s = c >> 8, rem = c & 255, hh = rem >> 5, dk = rem & 31;
      if (s == 0) {
        #pragma unroll
        for (int j = 0; j < 4; ++j) {
          float v = (acc[m][n][j] + bias[c]) * QSC;
          qb[(((b * H_ + hh) * T_) + t + j) * DK_ + dk] = f2bf(v);
        }
      } else if (s == 1) {
        #pragma unroll
        for (int j = 0; j < 4; ++j) {
          float v = acc[m][n][j] + bias[c];
          kb[(((b * H_ + hh) * T_) + t + j) * DK_ + dk] = f2bf(v);
        }
      } else {
        u16x4 pk;
        #pragma unroll
        for (int j = 0; j < 4; ++j) pk[j] = f2bf(acc[m][n][j] + bias[c]);
        // tiled V^T: [bh][t>>5][dk][t&31]
        *(u16x4*)(vt + (b * H_ + hh) * (DK_ * T_) +
                  ((t >> 5) * DK_ + dk) * 32 + (t & 31)) = pk;
      }
    }
}

// ---- attention: 32 q-rows/wave (2 Q frags), 4-wave 4-way split-K (R8, frozen)
__global__ __launch_bounds__(256) void k_attn(
    const unsigned short* __restrict__ qb, const unsigned short* __restrict__ kb,
    const unsigned short* __restrict__ vt, unsigned short* __restrict__ ob) {
  __shared__ float Osh[4][32][33];
  __shared__ float Lsh[4][32];
  int bh = blockIdx.y;
  int tid = threadIdx.x, lane = tid & 63, w = tid >> 6;  // w = k-quarter
  int g = lane >> 4, li = lane & 15;
  int q0 = blockIdx.x * 32;
  const unsigned short* Qp = qb + (bh * T_ + q0) * DK_;
  const unsigned short* Kp = kb + bh * T_ * DK_;
  const unsigned short* Vt = vt + bh * DK_ * T_;
  bf16x8 aq0 = as_bf(*(const u16x8*)(Qp + li * DK_ + g * 8));
  bf16x8 aq1 = as_bf(*(const u16x8*)(Qp + (16 + li) * DK_ + g * 8));
  float l_run0 = 0.f, l_run1 = 0.f;
  f32x4 oacc0[2] = {}, oacc1[2] = {};
  for (int kt = w * 256; kt < (w + 1) * 256; kt += 32) {
    bf16x8 bk0 = as_bf(*(const u16x8*)(Kp + (kt + li) * DK_ + g * 8));
    bf16x8 bk1 = as_bf(*(const u16x8*)(Kp + (kt + 16 + li) * DK_ + g * 8));
    const unsigned short* vtile = Vt + (kt >> 5) * (DK_ * 32);
    bf16x8 bv0 = as_bf(*(const u16x8*)(vtile + li * 32 + g * 8));
    bf16x8 bv1 = as_bf(*(const u16x8*)(vtile + (16 + li) * 32 + g * 8));
    f32x4 s0 = {}, s1 = {}, t0 = {}, t1 = {};
    __builtin_amdgcn_s_setprio(1);
    s0 = __builtin_amdgcn_mfma_f32_16x16x32_bf16(bk0, aq0, s0, 0, 0, 0);
    s1 = __builtin_amdgcn_mfma_f32_16x16x32_bf16(bk1, aq0, s1, 0, 0, 0);
    t0 = __builtin_amdgcn_mfma_f32_16x16x32_bf16(bk0, aq1, t0, 0, 0, 0);
    t1 = __builtin_amdgcn_mfma_f32_16x16x32_bf16(bk1, aq1, t1, 0, 0, 0);
    __builtin_amdgcn_s_setprio(0);
    {
      float p0[4], p1[4];
      #pragma unroll
      for (int j = 0; j < 4; ++j) {
        p0[j] = __builtin_amdgcn_exp2f(s0[j]);
        p1[j] = __builtin_amdgcn_exp2f(s1[j]);
      }
      l_run0 += ((p0[0] + p0[1]) + (p0[2] + p0[3])) +
                ((p1[0] + p1[1]) + (p1[2] + p1[3]));
      unsigned int c0, c1, c2, c3;
      asm("v_cvt_pk_bf16_f32 %0, %1, %2" : "=v"(c0) : "v"(p0[0]), "v"(p0[1]));
      asm("v_cvt_pk_bf16_f32 %0, %1, %2" : "=v"(c1) : "v"(p0[2]), "v"(p0[3]));
      asm("v_cvt_pk_bf16_f32 %0, %1, %2" : "=v"(c2) : "v"(p1[0]), "v"(p1[1]));
      asm("v_cvt_pk_bf16_f32 %0, %1, %2" : "=v"(c3) : "v"(p1[2]), "v"(p1[3]));
      asm("v_permlane32_swap_b32 %0, %1" : "+v"(c0), "+v"(c2));
      asm("v_permlane32_swap_b32 %0, %1" : "+v"(c1), "+v"(c3));
      asm("v_permlane16_swap_b32 %0, %1" : "+v"(c0), "+v"(c2));
      asm("v_permlane16_swap_b32 %0, %1" : "+v"(c1), "+v"(c3));
      u32x4 paw; paw[0] = c0; paw[1] = c1; paw[2] = c2; paw[3] = c3;
      bf16x8 pa = __builtin_bit_cast(bf16x8, paw);
      __builtin_amdgcn_s_setprio(1);
      oacc0[0] = __builtin_amdgcn_mfma_f32_16x16x32_bf16(pa, bv0, oacc0[0], 0, 0, 0);
      oacc0[1] = __builtin_amdgcn_mfma_f32_16x16x32_bf16(pa, bv1, oacc0[1], 0, 0, 0);
      __builtin_amdgcn_s_setprio(0);
    }
    {
      float p0[4], p1[4];
      #pragma unroll
      for (int j = 0; j < 4; ++j) {
        p0[j] = __builtin_amdgcn_exp2f(t0[j]);
        p1[j] = __builtin_amdgcn_exp2f(t1[j]);
      }
      l_run1 += ((p0[0] + p0[1]) + (p0[2] + p0[3])) +
                ((p1[0] + p1[1]) + (p1[2] + p1[3]));
      unsigned int c0, c1, c2, c3;
      asm("v_cvt_pk_bf16_f32 %0, %1, %2" : "=v"(c0) : "v"(p0[0]), "v"(p0[1]));
      asm("v_cvt_pk_bf16_f32 %0, %1, %2" : "=v"(c1) : "v"(p0[2]), "v"(p0[3]));
      asm("v_cvt_pk_bf16_f32 %0, %1, %2" : "=v"(c2) : "v"(p1[0]), "v"(p1[1]));
      asm("v_cvt_pk_bf16_f32 %0, %1, %2" : "=v"(c3) : "v"(p1[2]), "v"(p1[3]));
      asm("v_permlane32_swap_b32 %0, %1" : "+v"(c0), "+v"(c2));
      asm("v_permlane32_swap_b32 %0, %1" : "+v"(c1), "+v"(c3));
      asm("v_permlane16_swap_b32 %0, %1" : "+v"(c0), "+v"(c2));
      asm("v_permlane16_swap_b32 %0, %1" : "+v"(c1), "+v"(c3));
      u32x4 paw; paw[0] = c0; paw[1] = c1; paw[2] = c2; paw[3] = c3;
      bf16x8 pa = __builtin_bit_cast(bf16x8, paw);
      __builtin_amdgcn_s_setprio(1);
      oacc1[0] = __builtin_amdgcn_mfma_f32_16x16x32_bf16(pa, bv0, oacc1[0], 0, 0, 0);
      oacc1[1] = __builtin_amdgcn_mfma_f32_16x16x32_bf16(pa, bv1, oacc1[1], 0, 0, 0);
      __builtin_amdgcn_s_setprio(0);
    }
  }
  l_run0 += __shfl_xor(l_run0, 16);
  l_run0 += __shfl_xor(l_run0, 32);
  l_run1 += __shfl_xor(l_run1, 16);
  l_run1 += __shfl_xor(l_run1, 32);
  if (g == 0) { Lsh[w][li] = l_run0; Lsh[w][16 + li] = l_run1; }
  #pragma unroll
  for (int dh = 0; dh < 2; ++dh)
    #pragma unroll
    for (int j = 0; j < 4; ++j) {
      Osh[w][g * 4 + j][dh * 16 + li] = oacc0[dh][j];
      Osh[w][16 + g * 4 + j][dh * 16 + li] = oacc1[dh][j];
    }
  __syncthreads();
  if (tid < 128) {
    int q = tid & 31, dk0 = (tid >> 5) * 8;
    float l = (Lsh[0][q] + Lsh[1][q]) + (Lsh[2][q] + Lsh[3][q]);
    float rl = 1.0f / l;
    int b = bh >> 3, hh = bh & 7;
    u16x8 outv;
    #pragma unroll
    for (int i = 0; i < 8; ++i) {
      float o = (Osh[0][q][dk0 + i] + Osh[1][q][dk0 + i]) +
                (Osh[2][q][dk0 + i] + Osh[3][q][dk0 + i]);
      outv[i] = f2bf(o * rl);
    }
    *(u16x8*)(ob + ((b * T_ + q0 + q) * H_ + hh) * DK_ + dk0) = outv;
  }
}

// ------- fused out-proj + residual + LayerNorm: h = LN(ob@Wout+bout+h) -------
// 256 threads = 4 waves: wave (rg,ch) computes rows [rg*16,+16) x cols [ch*128,+128).
// B fragments from fragment-tiled Wout (coalesced 1KB segments, L2-resident).
__global__ __launch_bounds__(256) void k_outln(
    const unsigned short* __restrict__ A,    // BT x 256 bf16 (attn out)
    const unsigned short* __restrict__ Btf,  // ftiled [16][8][16][32]
    const float* __restrict__ bias,          // 256
    const float* __restrict__ gg, const float* __restrict__ bb,
    float* __restrict__ h,                   // in: residual, out: LN result
    unsigned short* __restrict__ hbf) {
  __shared__ float Ssh[2][2][16], Qsh[2][2][16];
  int tid = threadIdx.x, lane = tid & 63, w = tid >> 6;
  int g = lane >> 4, li = lane & 15;
  int rg = w >> 1, ch = w & 1;
  int row0 = blockIdx.x * 32 + rg * 16;
  int c0 = ch * 128;
  f32x4 acc[8] = {};
  for (int k0 = 0; k0 < 256; k0 += 32) {
    int kblk = k0 >> 5;
    bf16x8 af = as_bf(*(const u16x8*)(A + (row0 + li) * 256 + k0 + g * 8));
    #pragma unroll
    for (int n = 0; n < 8; ++n) {
      int nblk = ch * 8 + n;
      bf16x8 bf = as_bf(*(const u16x8*)(Btf + ((nblk * 8 + kblk) << 9) + li * 32 + g * 8));
      acc[n] = __builtin_amdgcn_mfma_f32_16x16x32_bf16(af, bf, acc[n], 0, 0, 0);
    }
  }
  // u = acc + bias + residual; per-row partial stats
  float uv[8][4];
  float s[4] = {0.f, 0.f, 0.f, 0.f}, q[4] = {0.f, 0.f, 0.f, 0.f};
  #pragma unroll
  for (int n = 0; n < 8; ++n) {
    int c = c0 + n * 16 + li;
    float bs = bias[c];
    #pragma unroll
    for (int j = 0; j < 4; ++j) {
      int r = row0 + g * 4 + j;
      float v = acc[n][j] + bs + h[r * 256 + c];
      uv[n][j] = v;
      s[j] += v; q[j] += v * v;
    }
  }
  #pragma unroll
  for (int j = 0; j < 4; ++j) {
    #pragma unroll
    for (int o = 1; o < 16; o <<= 1) {
      s[j] += __shfl_xor(s[j], o);
      q[j] += __shfl_xor(q[j], o);
    }
  }
  if (li == 0) {
    #pragma unroll
    for (int j = 0; j < 4; ++j) {
      Ssh[rg][ch][g * 4 + j] = s[j];
      Qsh[rg][ch][g * 4 + j] = q[j];
    }
  }
  __syncthreads();
  #pragma unroll
  for (int j = 0; j < 4; ++j) {
    int r = g * 4 + j;
    float st = Ssh[rg][0][r] + Ssh[rg][1][r];
    float qt = Qsh[rg][0][r] + Qsh[rg][1][r];
    float mean = st * (1.0f / D_);
    float var = qt * (1.0f / D_) - mean * mean;
    float rstd = rsqrtf(var + 1e-5f);
    s[j] = mean; q[j] = rstd;
  }
  #pragma unroll
  for (int n = 0; n < 8; ++n) {
    int c = c0 + n * 16 + li;
    float gv = gg[c], bv = bb[c];
    #pragma unroll
    for (int j = 0; j < 4; ++j) {
      int r = row0 + g * 4 + j;
      float y = (uv[n][j] - s[j]) * q[j] * gv + bv;
      h[r * 256 + c] = y;
      hbf[r * 256 + c] = f2bf(y);
    }
  }
}

// ---------------- final: out = h[:, -1, :] @ Wo + bo ----------------
__global__ void k_final(const float* __restrict__ h, const float* __restrict__ Wo,
                        const float* __restrict__ bo, float* __restrict__ out) {
  int tid = threadIdx.x;
  if (tid >= B_ * 3) return;
  int b = tid / 3, j = tid % 3;
  const float* hr = h + (b * T_ + (T_ - 1)) * D_;
  float acc = bo[j];
  for (int k = 0; k < D_; ++k) acc += hr[k] * Wo[k * 3 + j];
  out[tid] = acc;
}

extern "C" void kernel_launch(void* const* d_in, const int* in_sizes, int n_in,
                              void* d_out, int out_size, void* d_ws, size_t ws_size,
                              hipStream_t stream) {
  const float* x    = (const float*)d_in[0];
  const float* Wp   = (const float*)d_in[1];
  const float* bp   = (const float*)d_in[2];
  const float* pos  = (const float*)d_in[3];
  const float* Wqkv = (const float*)d_in[4];
  const float* bqkv = (const float*)d_in[5];
  const float* Wout = (const float*)d_in[6];
  const float* bout = (const float*)d_in[7];
  const float* ln_g = (const float*)d_in[8];
  const float* ln_b = (const float*)d_in[9];
  const float* Wo   = (const float*)d_in[10];
  const float* bo   = (const float*)d_in[11];

  char* ws = (char*)d_ws;
  float* h            = (float*)(ws);                        // 8 MB
  unsigned short* hbf = (unsigned short*)(ws + (16u << 20)); // 4 MB
  unsigned short* qb  = (unsigned short*)(ws + (20u << 20)); // 4 MB
  unsigned short* kb  = (unsigned short*)(ws + (24u << 20)); // 4 MB
  unsigned short* vt  = (unsigned short*)(ws + (28u << 20)); // 4 MB (tiled V^T)
  unsigned short* ob  = (unsigned short*)(ws + (32u << 20)); // 4 MB
  unsigned short* WqkvT = (unsigned short*)(ws + (36u << 20)); // 1.5 MB ftiled
  unsigned short* WoutT = (unsigned short*)(ws + (38u << 20)); // 0.5 MB ftiled

  k_wprep_f<<<dim3(48, 8, 4), 64, 0, stream>>>(Wqkv, WqkvT, 256, 768);
  k_wprep_f<<<dim3(16, 8, 4), 64, 0, stream>>>(Wout, WoutT, 256, 256);
  k_proj<<<BT_, 256, 0, stream>>>(x, Wp, bp, pos, h, hbf);
  for (int l = 0; l < L_; ++l) {
    k_gemm_qkv<<<dim3(BT_ / 64, 12), 256, 0, stream>>>(
        hbf, WqkvT + l * 768 * 256, bqkv + l * 768, qb, kb, vt);
    k_attn<<<dim3(T_ / 32, B_ * H_), 256, 0, stream>>>(qb, kb, vt, ob);
    k_outln<<<BT_ / 32, 256, 0, stream>>>(
        ob, WoutT + l * 256 * 256, bout + l * 256,
        ln_g + l * 256, ln_b + l * 256, h, hbf);
  }
  k_final<<<1, 64, 0, stream>>>(h, Wo, bo, (float*)d_out);
}

// Round 10
// 222.448 us; speedup vs baseline: 1.2885x; 1.0371x over previous
//
#include <hip/hip_runtime.h>
#include <hip/hip_bf16.h>

#define B_ 8
#define T_ 1024
#define IN_DIM_ 16
#define D_ 256
#define H_ 8
#define L_ 4
#define DK_ 32
#define BT_ (B_*T_)
#define LDT 72    // padded LDS stride for GEMM A tiles
#define LDO 264   // padded LDS stride for outln A tile (256+8)

typedef __attribute__((ext_vector_type(8))) __bf16 bf16x8;
typedef __attribute__((ext_vector_type(8))) unsigned short u16x8;
typedef __attribute__((ext_vector_type(4))) unsigned short u16x4;
typedef __attribute__((ext_vector_type(4))) float f32x4;
typedef __attribute__((ext_vector_type(4))) unsigned int u32x4;

static __device__ __forceinline__ unsigned short f2bf(float f) {
  union { float f; unsigned int u; } c{f};
  unsigned int u = c.u;
  u += 0x7fff + ((u >> 16) & 1);
  return (unsigned short)(u >> 16);
}
static __device__ __forceinline__ bf16x8 as_bf(u16x8 v) {
  return __builtin_bit_cast(bf16x8, v);
}

// ------- weight prep: f32 W[z][K][N] -> bf16 fragment-tiled [z][N/16][K/32][16][32]
__global__ __launch_bounds__(64) void k_wprep_f(
    const float* __restrict__ in, unsigned short* __restrict__ out,
    int K, int N) {
  int nb = blockIdx.x, kb = blockIdx.y, z = blockIdx.z;
  const float* inz = in + (size_t)z * K * N;
  unsigned short* outz = out + (size_t)z * K * N;
  int lane = threadIdx.x;
  int li = lane & 15, g = lane >> 4;
  int n = nb * 16 + li;
  int k0 = kb * 32 + g * 8;
  u16x8 v;
  #pragma unroll
  for (int j = 0; j < 8; ++j) v[j] = f2bf(inz[(k0 + j) * N + n]);
  *(u16x8*)(outz + ((nb * (K >> 5) + kb) << 9) + li * 32 + g * 8) = v;
}

// ---------------- input projection: h = x@Wp + bp + pos ----------------
__global__ __launch_bounds__(256) void k_proj(
    const float* __restrict__ x, const float* __restrict__ Wp,
    const float* __restrict__ bp, const float* __restrict__ pos,
    float* __restrict__ h, unsigned short* __restrict__ hbf) {
  int row = blockIdx.x;            // bt
  int c = threadIdx.x;             // 0..255
  int t = row & (T_ - 1);
  float acc = bp[c] + pos[t * D_ + c];
  const float* xr = x + row * IN_DIM_;
  #pragma unroll
  for (int k = 0; k < IN_DIM_; ++k) acc += xr[k] * Wp[k * D_ + c];
  h[row * D_ + c] = acc;
  hbf[row * D_ + c] = f2bf(acc);
}

// ------------- QKV GEMM: BM=128, A staged in LDS, B fragment-tiled from L2 -----
// q written PRE-SCALED by 1/sqrt(dk)*log2(e) -> attn does exp2(s) directly.
// q,k [b][h][t][dk]; v tiled-transposed [b][h][t/32][dk][32]
__global__ __launch_bounds__(256) void k_gemm_qkv(
    const unsigned short* __restrict__ A,    // BT x 256 bf16
    const unsigned short* __restrict__ Btf,  // ftiled [48][8][16][32]
    const float* __restrict__ bias,          // 768
    unsigned short* __restrict__ qb, unsigned short* __restrict__ kb,
    unsigned short* __restrict__ vt) {
  __shared__ unsigned short As[128 * LDT];
  int row0 = blockIdx.x * 128;
  int tid = threadIdx.x;
  int lane = tid & 63, w = tid >> 6;
  int g = lane >> 4, li = lane & 15;
  int wr = (w >> 1) * 64, wc = (w & 1) * 32;
  int col0 = blockIdx.y * 64;
  f32x4 acc[4][2] = {};
  for (int k0 = 0; k0 < 256; k0 += 64) {
    __syncthreads();
    int r = tid >> 1, kk = (tid & 1) * 32;
    const unsigned short* src = A + (row0 + r) * 256 + k0 + kk;
    unsigned short* dst = As + r * LDT + kk;
    *(u16x8*)(dst)      = *(const u16x8*)(src);
    *(u16x8*)(dst + 8)  = *(const u16x8*)(src + 8);
    *(u16x8*)(dst + 16) = *(const u16x8*)(src + 16);
    *(u16x8*)(dst + 24) = *(const u16x8*)(src + 24);
    __syncthreads();
    #pragma unroll
    for (int ks = 0; ks < 2; ++ks) {
      int kblk = (k0 >> 5) + ks;
      bf16x8 af[4], bfr[2];
      #pragma unroll
      for (int m = 0; m < 4; ++m)
        af[m] = as_bf(*(const u16x8*)(As + (wr + m * 16 + li) * LDT + ks * 32 + g * 8));
      #pragma unroll
      for (int n = 0; n < 2; ++n) {
        int nblk = (blockIdx.y << 2) + ((w & 1) << 1) + n;
        bfr[n] = as_bf(*(const u16x8*)(Btf + ((nblk * 8 + kblk) << 9) + li * 32 + g * 8));
      }
      #pragma unroll
      for (int m = 0; m < 4; ++m)
        #pragma unroll
        for (int n = 0; n < 2; ++n)
          acc[m][n] = __builtin_amdgcn_mfma_f32_16x16x32_bf16(af[m], bfr[n], acc[m][n], 0, 0, 0);
    }
  }
  const float QSC = 0.25505654f;  // (1/sqrt(32)) * log2(e)
  #pragma unroll
  for (int m = 0; m < 4; ++m)
    #pragma unroll
    for (int n = 0; n < 2; ++n) {
      int c = col0 + wc + n * 16 + li;
      int rbase = row0 + wr + m * 16 + g * 4;
      int b = rbase >> 10, t = rbase & (T_ - 1);
      int s = c >> 8, rem = c & 255, hh = rem >> 5, dk = rem & 31;
      if (s == 0) {
        #pragma unroll
        for (int j = 0; j < 4; ++j) {
          float v = (acc[m][n][j] + bias[c]) * QSC;
          qb[(((b * H_ + hh) * T_) + t + j) * DK_ + dk] = f2bf(v);
        }
      } else if (s == 1) {
        #pragma unroll
        for (int j = 0; j < 4; ++j) {
          float v = acc[m][n][j] + bias[c];
          kb[(((b * H_ + hh) * T_) + t + j) * DK_ + dk] = f2bf(v);
        }
      } else {
        u16x4 pk;
        #pragma unroll
        for (int j = 0; j < 4; ++j) pk[j] = f2bf(acc[m][n][j] + bias[c]);
        // tiled V^T: [bh][t>>5][dk][t&31]
        *(u16x4*)(vt + (b * H_ + hh) * (DK_ * T_) +
                  ((t >> 5) * DK_ + dk) * 32 + (t & 31)) = pk;
      }
    }
}

// ---- attention: 32 q-rows/wave (2 Q frags), 4-wave 4-way split-K (R8, frozen)
__global__ __launch_bounds__(256) void k_attn(
    const unsigned short* __restrict__ qb, const unsigned short* __restrict__ kb,
    const unsigned short* __restrict__ vt, unsigned short* __restrict__ ob) {
  __shared__ float Osh[4][32][33];
  __shared__ float Lsh[4][32];
  int bh = blockIdx.y;
  int tid = threadIdx.x, lane = tid & 63, w = tid >> 6;  // w = k-quarter
  int g = lane >> 4, li = lane & 15;
  int q0 = blockIdx.x * 32;
  const unsigned short* Qp = qb + (bh * T_ + q0) * DK_;
  const unsigned short* Kp = kb + bh * T_ * DK_;
  const unsigned short* Vt = vt + bh * DK_ * T_;
  bf16x8 aq0 = as_bf(*(const u16x8*)(Qp + li * DK_ + g * 8));
  bf16x8 aq1 = as_bf(*(const u16x8*)(Qp + (16 + li) * DK_ + g * 8));
  float l_run0 = 0.f, l_run1 = 0.f;
  f32x4 oacc0[2] = {}, oacc1[2] = {};
  for (int kt = w * 256; kt < (w + 1) * 256; kt += 32) {
    bf16x8 bk0 = as_bf(*(const u16x8*)(Kp + (kt + li) * DK_ + g * 8));
    bf16x8 bk1 = as_bf(*(const u16x8*)(Kp + (kt + 16 + li) * DK_ + g * 8));
    const unsigned short* vtile = Vt + (kt >> 5) * (DK_ * 32);
    bf16x8 bv0 = as_bf(*(const u16x8*)(vtile + li * 32 + g * 8));
    bf16x8 bv1 = as_bf(*(const u16x8*)(vtile + (16 + li) * 32 + g * 8));
    f32x4 s0 = {}, s1 = {}, t0 = {}, t1 = {};
    __builtin_amdgcn_s_setprio(1);
    s0 = __builtin_amdgcn_mfma_f32_16x16x32_bf16(bk0, aq0, s0, 0, 0, 0);
    s1 = __builtin_amdgcn_mfma_f32_16x16x32_bf16(bk1, aq0, s1, 0, 0, 0);
    t0 = __builtin_amdgcn_mfma_f32_16x16x32_bf16(bk0, aq1, t0, 0, 0, 0);
    t1 = __builtin_amdgcn_mfma_f32_16x16x32_bf16(bk1, aq1, t1, 0, 0, 0);
    __builtin_amdgcn_s_setprio(0);
    {
      float p0[4], p1[4];
      #pragma unroll
      for (int j = 0; j < 4; ++j) {
        p0[j] = __builtin_amdgcn_exp2f(s0[j]);
        p1[j] = __builtin_amdgcn_exp2f(s1[j]);
      }
      l_run0 += ((p0[0] + p0[1]) + (p0[2] + p0[3])) +
                ((p1[0] + p1[1]) + (p1[2] + p1[3]));
      unsigned int c0, c1, c2, c3;
      asm("v_cvt_pk_bf16_f32 %0, %1, %2" : "=v"(c0) : "v"(p0[0]), "v"(p0[1]));
      asm("v_cvt_pk_bf16_f32 %0, %1, %2" : "=v"(c1) : "v"(p0[2]), "v"(p0[3]));
      asm("v_cvt_pk_bf16_f32 %0, %1, %2" : "=v"(c2) : "v"(p1[0]), "v"(p1[1]));
      asm("v_cvt_pk_bf16_f32 %0, %1, %2" : "=v"(c3) : "v"(p1[2]), "v"(p1[3]));
      asm("v_permlane32_swap_b32 %0, %1" : "+v"(c0), "+v"(c2));
      asm("v_permlane32_swap_b32 %0, %1" : "+v"(c1), "+v"(c3));
      asm("v_permlane16_swap_b32 %0, %1" : "+v"(c0), "+v"(c2));
      asm("v_permlane16_swap_b32 %0, %1" : "+v"(c1), "+v"(c3));
      u32x4 paw; paw[0] = c0; paw[1] = c1; paw[2] = c2; paw[3] = c3;
      bf16x8 pa = __builtin_bit_cast(bf16x8, paw);
      __builtin_amdgcn_s_setprio(1);
      oacc0[0] = __builtin_amdgcn_mfma_f32_16x16x32_bf16(pa, bv0, oacc0[0], 0, 0, 0);
      oacc0[1] = __builtin_amdgcn_mfma_f32_16x16x32_bf16(pa, bv1, oacc0[1], 0, 0, 0);
      __builtin_amdgcn_s_setprio(0);
    }
    {
      float p0[4], p1[4];
      #pragma unroll
      for (int j = 0; j < 4; ++j) {
        p0[j] = __builtin_amdgcn_exp2f(t0[j]);
        p1[j] = __builtin_amdgcn_exp2f(t1[j]);
      }
      l_run1 += ((p0[0] + p0[1]) + (p0[2] + p0[3])) +
                ((p1[0] + p1[1]) + (p1[2] + p1[3]));
      unsigned int c0, c1, c2, c3;
      asm("v_cvt_pk_bf16_f32 %0, %1, %2" : "=v"(c0) : "v"(p0[0]), "v"(p0[1]));
      asm("v_cvt_pk_bf16_f32 %0, %1, %2" : "=v"(c1) : "v"(p0[2]), "v"(p0[3]));
      asm("v_cvt_pk_bf16_f32 %0, %1, %2" : "=v"(c2) : "v"(p1[0]), "v"(p1[1]));
      asm("v_cvt_pk_bf16_f32 %0, %1, %2" : "=v"(c3) : "v"(p1[2]), "v"(p1[3]));
      asm("v_permlane32_swap_b32 %0, %1" : "+v"(c0), "+v"(c2));
      asm("v_permlane32_swap_b32 %0, %1" : "+v"(c1), "+v"(c3));
      asm("v_permlane16_swap_b32 %0, %1" : "+v"(c0), "+v"(c2));
      asm("v_permlane16_swap_b32 %0, %1" : "+v"(c1), "+v"(c3));
      u32x4 paw; paw[0] = c0; paw[1] = c1; paw[2] = c2; paw[3] = c3;
      bf16x8 pa = __builtin_bit_cast(bf16x8, paw);
      __builtin_amdgcn_s_setprio(1);
      oacc1[0] = __builtin_amdgcn_mfma_f32_16x16x32_bf16(pa, bv0, oacc1[0], 0, 0, 0);
      oacc1[1] = __builtin_amdgcn_mfma_f32_16x16x32_bf16(pa, bv1, oacc1[1], 0, 0, 0);
      __builtin_amdgcn_s_setprio(0);
    }
  }
  l_run0 += __shfl_xor(l_run0, 16);
  l_run0 += __shfl_xor(l_run0, 32);
  l_run1 += __shfl_xor(l_run1, 16);
  l_run1 += __shfl_xor(l_run1, 32);
  if (g == 0) { Lsh[w][li] = l_run0; Lsh[w][16 + li] = l_run1; }
  #pragma unroll
  for (int dh = 0; dh < 2; ++dh)
    #pragma unroll
    for (int j = 0; j < 4; ++j) {
      Osh[w][g * 4 + j][dh * 16 + li] = oacc0[dh][j];
      Osh[w][16 + g * 4 + j][dh * 16 + li] = oacc1[dh][j];
    }
  __syncthreads();
  if (tid < 128) {
    int q = tid & 31, dk0 = (tid >> 5) * 8;
    float l = (Lsh[0][q] + Lsh[1][q]) + (Lsh[2][q] + Lsh[3][q]);
    float rl = 1.0f / l;
    int b = bh >> 3, hh = bh & 7;
    u16x8 outv;
    #pragma unroll
    for (int i = 0; i < 8; ++i) {
      float o = (Osh[0][q][dk0 + i] + Osh[1][q][dk0 + i]) +
                (Osh[2][q][dk0 + i] + Osh[3][q][dk0 + i]);
      outv[i] = f2bf(o * rl);
    }
    *(u16x8*)(ob + ((b * T_ + q0 + q) * H_ + hh) * DK_ + dk0) = outv;
  }
}

// ------- fused out-proj + residual + LayerNorm: h = LN(ob@Wout+bout+h) -------
// A tile (32 rows x 256) staged in LDS once (coalesced), frags via ds_read_b128.
// B from fragment-tiled Wout (coalesced 1KB segments, L2-resident).
__global__ __launch_bounds__(256) void k_outln(
    const unsigned short* __restrict__ A,    // BT x 256 bf16 (attn out)
    const unsigned short* __restrict__ Btf,  // ftiled [16][8][16][32]
    const float* __restrict__ bias,          // 256
    const float* __restrict__ gg, const float* __restrict__ bb,
    float* __restrict__ h,                   // in: residual, out: LN result
    unsigned short* __restrict__ hbf) {
  __shared__ unsigned short Asp[32 * LDO];
  __shared__ float Ssh[2][2][16], Qsh[2][2][16];
  int tid = threadIdx.x, lane = tid & 63, w = tid >> 6;
  int g = lane >> 4, li = lane & 15;
  int rg = w >> 1, ch = w & 1;
  int row0 = blockIdx.x * 32;
  int c0 = ch * 128;
  {  // stage A tile 32x256 coalesced: thread t -> row t>>3, 64B chunk (t&7)*32
    int r = tid >> 3, kk = (tid & 7) * 32;
    const unsigned short* src = A + (row0 + r) * 256 + kk;
    unsigned short* dst = Asp + r * LDO + kk;
    *(u16x8*)(dst)      = *(const u16x8*)(src);
    *(u16x8*)(dst + 8)  = *(const u16x8*)(src + 8);
    *(u16x8*)(dst + 16) = *(const u16x8*)(src + 16);
    *(u16x8*)(dst + 24) = *(const u16x8*)(src + 24);
  }
  __syncthreads();
  int rowb = rg * 16;  // this wave's rows within the tile
  f32x4 acc[8] = {};
  for (int k0 = 0; k0 < 256; k0 += 32) {
    int kblk = k0 >> 5;
    bf16x8 af = as_bf(*(const u16x8*)(Asp + (rowb + li) * LDO + k0 + g * 8));
    #pragma unroll
    for (int n = 0; n < 8; ++n) {
      int nblk = ch * 8 + n;
      bf16x8 bf = as_bf(*(const u16x8*)(Btf + ((nblk * 8 + kblk) << 9) + li * 32 + g * 8));
      acc[n] = __builtin_amdgcn_mfma_f32_16x16x32_bf16(af, bf, acc[n], 0, 0, 0);
    }
  }
  int row0w = row0 + rowb;
  // u = acc + bias + residual; per-row partial stats
  float uv[8][4];
  float s[4] = {0.f, 0.f, 0.f, 0.f}, q[4] = {0.f, 0.f, 0.f, 0.f};
  #pragma unroll
  for (int n = 0; n < 8; ++n) {
    int c = c0 + n * 16 + li;
    float bs = bias[c];
    #pragma unroll
    for (int j = 0; j < 4; ++j) {
      int r = row0w + g * 4 + j;
      float v = acc[n][j] + bs + h[r * 256 + c];
      uv[n][j] = v;
      s[j] += v; q[j] += v * v;
    }
  }
  #pragma unroll
  for (int j = 0; j < 4; ++j) {
    #pragma unroll
    for (int o = 1; o < 16; o <<= 1) {
      s[j] += __shfl_xor(s[j], o);
      q[j] += __shfl_xor(q[j], o);
    }
  }
  if (li == 0) {
    #pragma unroll
    for (int j = 0; j < 4; ++j) {
      Ssh[rg][ch][g * 4 + j] = s[j];
      Qsh[rg][ch][g * 4 + j] = q[j];
    }
  }
  __syncthreads();
  #pragma unroll
  for (int j = 0; j < 4; ++j) {
    int r = g * 4 + j;
    float st = Ssh[rg][0][r] + Ssh[rg][1][r];
    float qt = Qsh[rg][0][r] + Qsh[rg][1][r];
    float mean = st * (1.0f / D_);
    float var = qt * (1.0f / D_) - mean * mean;
    float rstd = rsqrtf(var + 1e-5f);
    s[j] = mean; q[j] = rstd;
  }
  #pragma unroll
  for (int n = 0; n < 8; ++n) {
    int c = c0 + n * 16 + li;
    float gv = gg[c], bv = bb[c];
    #pragma unroll
    for (int j = 0; j < 4; ++j) {
      int r = row0w + g * 4 + j;
      float y = (uv[n][j] - s[j]) * q[j] * gv + bv;
      h[r * 256 + c] = y;
      hbf[r * 256 + c] = f2bf(y);
    }
  }
}

// ---------------- final: out = h[:, -1, :] @ Wo + bo ----------------
__global__ void k_final(const float* __restrict__ h, const float* __restrict__ Wo,
                        const float* __restrict__ bo, float* __restrict__ out) {
  int tid = threadIdx.x;
  if (tid >= B_ * 3) return;
  int b = tid / 3, j = tid % 3;
  const float* hr = h + (b * T_ + (T_ - 1)) * D_;
  float acc = bo[j];
  for (int k = 0; k < D_; ++k) acc += hr[k] * Wo[k * 3 + j];
  out[tid] = acc;
}

extern "C" void kernel_launch(void* const* d_in, const int* in_sizes, int n_in,
                              void* d_out, int out_size, void* d_ws, size_t ws_size,
                              hipStream_t stream) {
  const float* x    = (const float*)d_in[0];
  const float* Wp   = (const float*)d_in[1];
  const float* bp   = (const float*)d_in[2];
  const float* pos  = (const float*)d_in[3];
  const float* Wqkv = (const float*)d_in[4];
  const float* bqkv = (const float*)d_in[5];
  const float* Wout = (const float*)d_in[6];
  const float* bout = (const float*)d_in[7];
  const float* ln_g = (const float*)d_in[8];
  const float* ln_b = (const float*)d_in[9];
  const float* Wo   = (const float*)d_in[10];
  const float* bo   = (const float*)d_in[11];

  char* ws = (char*)d_ws;
  float* h            = (float*)(ws);                        // 8 MB
  unsigned short* hbf = (unsigned short*)(ws + (16u << 20)); // 4 MB
  unsigned short* qb  = (unsigned short*)(ws + (20u << 20)); // 4 MB
  unsigned short* kb  = (unsigned short*)(ws + (24u << 20)); // 4 MB
  unsigned short* vt  = (unsigned short*)(ws + (28u << 20)); // 4 MB (tiled V^T)
  unsigned short* ob  = (unsigned short*)(ws + (32u << 20)); // 4 MB
  unsigned short* WqkvT = (unsigned short*)(ws + (36u << 20)); // 1.5 MB ftiled
  unsigned short* WoutT = (unsigned short*)(ws + (38u << 20)); // 0.5 MB ftiled

  k_wprep_f<<<dim3(48, 8, 4), 64, 0, stream>>>(Wqkv, WqkvT, 256, 768);
  k_wprep_f<<<dim3(16, 8, 4), 64, 0, stream>>>(Wout, WoutT, 256, 256);
  k_proj<<<BT_, 256, 0, stream>>>(x, Wp, bp, pos, h, hbf);
  for (int l = 0; l < L_; ++l) {
    k_gemm_qkv<<<dim3(BT_ / 128, 12), 256, 0, stream>>>(
        hbf, WqkvT + l * 768 * 256, bqkv + l * 768, qb, kb, vt);
    k_attn<<<dim3(T_ / 32, B_ * H_), 256, 0, stream>>>(qb, kb, vt, ob);
    k_outln<<<BT_ / 32, 256, 0, stream>>>(
        ob, WoutT + l * 256 * 256, bout + l * 256,
        ln_g + l * 256, ln_b + l * 256, h, hbf);
  }
  k_final<<<1, 64, 0, stream>>>(h, Wo, bo, (float*)d_out);
}